// Round 9
// baseline (313.922 us; speedup 1.0000x reference)
//
#include <hip/hip_runtime.h>
#include <hip/hip_fp16.h>
#include <math.h>

// ---------------- degree histogram + per-edge rank + packed (rank,src) ----------------
__global__ void hist_kernel(const int* __restrict__ src, const int* __restrict__ dst,
                            int* __restrict__ counts, unsigned* __restrict__ pack, int E) {
    int e = blockIdx.x * blockDim.x + threadIdx.x;
    if (e < E) {
        int r = atomicAdd(&counts[dst[e]], 1);
        pack[e] = ((unsigned)r << 17) | (unsigned)src[e];
    }
}

// ---------------- exclusive scan ----------------
__global__ void scan1_kernel(const int* __restrict__ counts, int* __restrict__ rowptr,
                             int* __restrict__ partials, int n) {
    __shared__ int tsum[256];
    int chunk = blockIdx.x;
    int base = chunk * 1024;
    int t = threadIdx.x;
    int v[4];
    int s = 0;
    #pragma unroll
    for (int j = 0; j < 4; ++j) {
        int idx = base + t * 4 + j;
        v[j] = (idx < n) ? counts[idx] : 0;
        s += v[j];
    }
    tsum[t] = s;
    __syncthreads();
    for (int off = 1; off < 256; off <<= 1) {
        int add = (t >= off) ? tsum[t - off] : 0;
        __syncthreads();
        tsum[t] += add;
        __syncthreads();
    }
    if (t == 255) partials[chunk] = tsum[255];
    int run = (t == 0) ? 0 : tsum[t - 1];
    #pragma unroll
    for (int j = 0; j < 4; ++j) {
        int idx = base + t * 4 + j;
        if (idx < n) rowptr[idx] = run;
        run += v[j];
    }
}

__global__ void scan2_kernel(int* __restrict__ partials, int nch) {
    __shared__ int s[128];
    int t = threadIdx.x;  // blockDim = 128
    s[t] = (t < nch) ? partials[t] : 0;
    __syncthreads();
    for (int off = 1; off < 128; off <<= 1) {
        int add = (t >= off) ? s[t - off] : 0;
        __syncthreads();
        s[t] += add;
        __syncthreads();
    }
    if (t < nch) partials[t] = (t == 0) ? 0 : s[t - 1];
}

// scan3 (merged): finalize rowptr/rowend, dinv, and conv1 pre-scale xs[n,16].
// One thread per (node, c) with c in [0,16).
__global__ void scan3_kernel(int* __restrict__ rowptr, const int* __restrict__ partials,
                             const int* __restrict__ counts, int* __restrict__ rowend,
                             float* __restrict__ dinv, const float* __restrict__ x,
                             __half* __restrict__ xs, int n) {
    int i = blockIdx.x * blockDim.x + threadIdx.x;
    if (i >= n * 16) return;
    int node = i >> 4, c = i & 15;
    int cnt = counts[node];
    float dv = rsqrtf((float)cnt + 1.0f);
    if (c == 0) {
        int v = rowptr[node] + partials[node >> 10];
        rowptr[node] = v;
        rowend[node] = v + cnt;
        dinv[node] = dv;
    }
    float xv = (c < 13) ? x[node * 13 + c] * dv : 0.f;
    xs[i] = __float2half(xv);
}

// ---------------- CSR fill: atomic-free, XCD-partitioned ----------------
__global__ void fillx_kernel(const int* __restrict__ dst, const unsigned* __restrict__ pack,
                             const int* __restrict__ rowptr, int* __restrict__ csr_src,
                             int E, int N) {
    int x = blockIdx.x & 7;
    int grp = blockIdx.x >> 3;
    int ngrp = gridDim.x >> 3;
    int lo = (int)(((long long)N * x) >> 3);
    int hi = (int)(((long long)N * (x + 1)) >> 3);
    int chunk = (E + ngrp - 1) / ngrp;
    int e0 = grp * chunk;
    int e1 = min(E, e0 + chunk);
    for (int e = e0 + (int)threadIdx.x; e < e1; e += (int)blockDim.x) {
        int d = dst[e];
        if (d >= lo && d < hi) {
            unsigned w = pack[e];
            csr_src[rowptr[d] + (int)(w >> 17)] = (int)(w & 0x1FFFFu);
        }
    }
}

// ---------------- 16-wide aggregation: 16 edges/instr, clamped loads ----------------
// Lane (q=lane>>2, l=lane&3): slot q handles edge base+q; lane loads 8B (4 halves) =
// features [l*4, l*4+4) of the 32B source row. All loads unconditional (clamped index),
// adds predicated. Butterfly xor{4,8,16,32}; quad 0 epilogue.
__global__ void agg16_kernel(const __half* __restrict__ xs, const int* __restrict__ rowptr,
                             const int* __restrict__ rowend, const int* __restrict__ csr_src,
                             const float* __restrict__ dinv, float* __restrict__ a1, int n) {
    int node = __builtin_amdgcn_readfirstlane(blockIdx.x * 4 + (int)(threadIdx.x >> 6));
    int lane = threadIdx.x & 63;
    if (node >= n) return;
    int q = lane >> 2, l = lane & 3;
    const char* Xb = (const char*)xs;
    float s0 = 0.f, s1 = 0.f, s2 = 0.f, s3 = 0.f;
    if (q == 0) {  // self-loop
        float2 raw = *(const float2*)(Xb + ((size_t)node << 5) + (l << 3));
        union { float2 f; __half2 h[2]; } u; u.f = raw;
        float2 a = __half22float2(u.h[0]), b = __half22float2(u.h[1]);
        s0 = a.x; s1 = a.y; s2 = b.x; s3 = b.y;
    }
    int e0 = rowptr[node], end = rowend[node];
    for (int base = e0; base < end; base += 16) {
        int idx = base + q;
        int sj = csr_src[idx < end ? idx : end - 1];
        float2 raw = *(const float2*)(Xb + ((size_t)sj << 5) + (l << 3));
        union { float2 f; __half2 h[2]; } u; u.f = raw;
        float2 a = __half22float2(u.h[0]), b = __half22float2(u.h[1]);
        if (idx < end) { s0 += a.x; s1 += a.y; s2 += b.x; s3 += b.y; }
    }
    s0 += __shfl_xor(s0, 4); s0 += __shfl_xor(s0, 8); s0 += __shfl_xor(s0, 16); s0 += __shfl_xor(s0, 32);
    s1 += __shfl_xor(s1, 4); s1 += __shfl_xor(s1, 8); s1 += __shfl_xor(s1, 16); s1 += __shfl_xor(s1, 32);
    s2 += __shfl_xor(s2, 4); s2 += __shfl_xor(s2, 8); s2 += __shfl_xor(s2, 16); s2 += __shfl_xor(s2, 32);
    s3 += __shfl_xor(s3, 4); s3 += __shfl_xor(s3, 8); s3 += __shfl_xor(s3, 16); s3 += __shfl_xor(s3, 32);
    if (q == 0) {
        float dv = dinv[node];
        float4 o; o.x = s0 * dv; o.y = s1 * dv; o.z = s2 * dv; o.w = s3 * dv;
        *(float4*)(a1 + ((size_t)node << 4) + (l << 2)) = o;
    }
}

// ---------------- conv1 matmul: x1 = relu(a1 @ W1 + b1), K=13 (stride 16) ----------------
__global__ void matmul13_kernel(const float* __restrict__ a1, const float* __restrict__ W1,
                                const float* __restrict__ b1, float* __restrict__ x1, int n) {
    __shared__ float w[13 * 64];
    for (int i = threadIdx.x; i < 13 * 64; i += 256) w[i] = W1[i];
    __syncthreads();
    int row = blockIdx.x * 4 + (threadIdx.x >> 6);
    int col = threadIdx.x & 63;
    if (row >= n) return;
    const float* ar = a1 + (size_t)row * 16;
    float acc = b1[col];
    #pragma unroll
    for (int k = 0; k < 13; ++k) acc = fmaf(ar[k], w[k * 64 + col], acc);
    x1[(size_t)row * 64 + col] = fmaxf(acc, 0.f);
}

// ---------------- conv2 matmul: register-resident W, K split across quarters ----------------
__global__ void matmul_scale64(const float* __restrict__ X, const float* __restrict__ W,
                               const float* __restrict__ dinv, __half* __restrict__ G, int n) {
    int lane = threadIdx.x & 63;
    int wave = threadIdx.x >> 6;  // 0..3
    int f = lane & 15, q = lane >> 4;
    const float4* W4 = (const float4*)W;  // W[64][64] -> W4[k*16 + c4]
    float4 wr[16];
    #pragma unroll
    for (int kk = 0; kk < 16; ++kk) wr[kk] = W4[(q * 16 + kk) * 16 + f];
    int base = blockIdx.x * 32 + wave * 8;
    #pragma unroll 2
    for (int r = 0; r < 8; ++r) {
        int row = base + r;
        if (row >= n) break;
        const float4* xr = (const float4*)(X + (size_t)row * 64);
        float4 xa = xr[q * 4 + 0], xb = xr[q * 4 + 1];
        float4 xc = xr[q * 4 + 2], xd = xr[q * 4 + 3];
        float xv[16] = {xa.x, xa.y, xa.z, xa.w, xb.x, xb.y, xb.z, xb.w,
                        xc.x, xc.y, xc.z, xc.w, xd.x, xd.y, xd.z, xd.w};
        float a0 = 0.f, a1_ = 0.f, a2 = 0.f, a3 = 0.f;
        #pragma unroll
        for (int kk = 0; kk < 16; ++kk) {
            a0 = fmaf(xv[kk], wr[kk].x, a0);
            a1_ = fmaf(xv[kk], wr[kk].y, a1_);
            a2 = fmaf(xv[kk], wr[kk].z, a2);
            a3 = fmaf(xv[kk], wr[kk].w, a3);
        }
        a0 += __shfl_xor(a0, 16); a0 += __shfl_xor(a0, 32);
        a1_ += __shfl_xor(a1_, 16); a1_ += __shfl_xor(a1_, 32);
        a2 += __shfl_xor(a2, 16); a2 += __shfl_xor(a2, 32);
        a3 += __shfl_xor(a3, 16); a3 += __shfl_xor(a3, 32);
        if (q == 0) {
            float dv = dinv[row];
            union { __half2 h[2]; float2 fx; } u;
            u.h[0] = __floats2half2_rn(a0 * dv, a1_ * dv);
            u.h[1] = __floats2half2_rn(a2 * dv, a3 * dv);
            *(float2*)((char*)G + ((size_t)row << 7) + (f << 3)) = u.fx;
        }
    }
}

// conv3 matmul: 64 -> 10, padded to 16 cols (pad cols written as 0), half output
__global__ void matmul_scale10(const float* __restrict__ X, const float* __restrict__ W,
                               const float* __restrict__ dinv, __half* __restrict__ G, int n) {
    __shared__ float w[64 * 10];
    for (int i = threadIdx.x; i < 640; i += 256) w[i] = W[i];
    __syncthreads();
    int row = blockIdx.x * 16 + (threadIdx.x >> 4);
    int col = threadIdx.x & 15;
    if (row >= n) return;
    float r = 0.f;
    if (col < 10) {
        const float* xr = X + (size_t)row * 64;
        float acc = 0.f;
        #pragma unroll
        for (int k = 0; k < 64; ++k) acc = fmaf(xr[k], w[k * 10 + col], acc);
        r = acc * dinv[row];
    }
    G[(size_t)row * 16 + col] = __float2half(r);
}

// ---------------- 64-wide aggregation: 8 edges/instr, clamped loads ----------------
// Octet o=lane>>3 handles one edge; lane loads 16B (8 halves) = features [l*8,l*8+8).
// Loads unconditional (clamped), adds predicated. Butterfly xor{8,16,32}; octet 0 epilogue.
template <bool RELU, bool RESID>
__global__ void agg64_kernel(const __half* __restrict__ G, const int* __restrict__ rowptr,
                             const int* __restrict__ rowend, const int* __restrict__ csr_src,
                             const float* __restrict__ dinv, const float* __restrict__ bias,
                             const float* __restrict__ resid, float* __restrict__ out, int n) {
    int node = __builtin_amdgcn_readfirstlane(blockIdx.x * 4 + (int)(threadIdx.x >> 6));
    int lane = threadIdx.x & 63;
    if (node >= n) return;
    int o = lane >> 3;   // edge slot within 8-edge packet
    int l = lane & 7;    // feature group: features [l*8, l*8+8)
    const char* Gb = (const char*)G;
    float s0 = 0.f, s1 = 0.f, s2 = 0.f, s3 = 0.f, s4 = 0.f, s5 = 0.f, s6 = 0.f, s7 = 0.f;
    if (o == 0) {  // self-loop term
        float4 raw = *(const float4*)(Gb + ((size_t)node << 7) + (l << 4));
        union { float4 f; __half2 h[4]; } u; u.f = raw;
        float2 a = __half22float2(u.h[0]), b = __half22float2(u.h[1]);
        float2 c = __half22float2(u.h[2]), d = __half22float2(u.h[3]);
        s0 = a.x; s1 = a.y; s2 = b.x; s3 = b.y; s4 = c.x; s5 = c.y; s6 = d.x; s7 = d.y;
    }
    int e0 = rowptr[node], end = rowend[node];
    for (int base = e0; base < end; base += 16) {
        #pragma unroll
        for (int uu = 0; uu < 2; ++uu) {
            int idx = base + uu * 8 + o;
            int sj = csr_src[idx < end ? idx : end - 1];  // uniform within octet
            float4 raw = *(const float4*)(Gb + ((size_t)sj << 7) + (l << 4));
            union { float4 f; __half2 h[4]; } u; u.f = raw;
            float2 a = __half22float2(u.h[0]), b = __half22float2(u.h[1]);
            float2 c = __half22float2(u.h[2]), d = __half22float2(u.h[3]);
            if (idx < end) {
                s0 += a.x; s1 += a.y; s2 += b.x; s3 += b.y;
                s4 += c.x; s5 += c.y; s6 += d.x; s7 += d.y;
            }
        }
    }
    s0 += __shfl_xor(s0, 8); s0 += __shfl_xor(s0, 16); s0 += __shfl_xor(s0, 32);
    s1 += __shfl_xor(s1, 8); s1 += __shfl_xor(s1, 16); s1 += __shfl_xor(s1, 32);
    s2 += __shfl_xor(s2, 8); s2 += __shfl_xor(s2, 16); s2 += __shfl_xor(s2, 32);
    s3 += __shfl_xor(s3, 8); s3 += __shfl_xor(s3, 16); s3 += __shfl_xor(s3, 32);
    s4 += __shfl_xor(s4, 8); s4 += __shfl_xor(s4, 16); s4 += __shfl_xor(s4, 32);
    s5 += __shfl_xor(s5, 8); s5 += __shfl_xor(s5, 16); s5 += __shfl_xor(s5, 32);
    s6 += __shfl_xor(s6, 8); s6 += __shfl_xor(s6, 16); s6 += __shfl_xor(s6, 32);
    s7 += __shfl_xor(s7, 8); s7 += __shfl_xor(s7, 16); s7 += __shfl_xor(s7, 32);
    if (o == 0) {
        float dv = dinv[node];
        const float* bp = bias + (l << 3);
        float4 ba = *(const float4*)bp, bb = *(const float4*)(bp + 4);
        float v0 = s0 * dv + ba.x, v1 = s1 * dv + ba.y, v2 = s2 * dv + ba.z, v3 = s3 * dv + ba.w;
        float v4 = s4 * dv + bb.x, v5 = s5 * dv + bb.y, v6 = s6 * dv + bb.z, v7 = s7 * dv + bb.w;
        if (RELU) {
            v0 = fmaxf(v0, 0.f); v1 = fmaxf(v1, 0.f); v2 = fmaxf(v2, 0.f); v3 = fmaxf(v3, 0.f);
            v4 = fmaxf(v4, 0.f); v5 = fmaxf(v5, 0.f); v6 = fmaxf(v6, 0.f); v7 = fmaxf(v7, 0.f);
        }
        if (RESID) {
            const float* rp = resid + ((size_t)node << 6) + (l << 3);
            float4 ra = *(const float4*)rp, rb = *(const float4*)(rp + 4);
            v0 += ra.x; v1 += ra.y; v2 += ra.z; v3 += ra.w;
            v4 += rb.x; v5 += rb.y; v6 += rb.z; v7 += rb.w;
        }
        float* op = out + ((size_t)node << 6) + (l << 3);
        float4 oa; oa.x = v0; oa.y = v1; oa.z = v2; oa.w = v3;
        float4 ob; ob.x = v4; ob.y = v5; ob.z = v6; ob.w = v7;
        *(float4*)op = oa;
        *(float4*)(op + 4) = ob;
    }
}

// ---------------- final aggregation (16 edges/instr, clamped) + fused log_softmax ----------------
__global__ void agg10_lsm_kernel(const __half* __restrict__ G, const int* __restrict__ rowptr,
                                 const int* __restrict__ rowend, const int* __restrict__ csr_src,
                                 const float* __restrict__ dinv, const float* __restrict__ bias,
                                 float* __restrict__ out, int n) {
    int node = __builtin_amdgcn_readfirstlane(blockIdx.x * 4 + (int)(threadIdx.x >> 6));
    int lane = threadIdx.x & 63;
    if (node >= n) return;
    int q = lane >> 2, l = lane & 3;
    const char* Gb = (const char*)G;
    float s0 = 0.f, s1 = 0.f, s2 = 0.f, s3 = 0.f;
    if (q == 0) {  // self-loop (pad cols hold 0)
        float2 raw = *(const float2*)(Gb + ((size_t)node << 5) + (l << 3));
        union { float2 f; __half2 h[2]; } u; u.f = raw;
        float2 a = __half22float2(u.h[0]), b = __half22float2(u.h[1]);
        s0 = a.x; s1 = a.y; s2 = b.x; s3 = b.y;
    }
    int e0 = rowptr[node], end = rowend[node];
    for (int base = e0; base < end; base += 16) {
        int idx = base + q;
        int sj = csr_src[idx < end ? idx : end - 1];
        float2 raw = *(const float2*)(Gb + ((size_t)sj << 5) + (l << 3));
        union { float2 f; __half2 h[2]; } u; u.f = raw;
        float2 a = __half22float2(u.h[0]), b = __half22float2(u.h[1]);
        if (idx < end) { s0 += a.x; s1 += a.y; s2 += b.x; s3 += b.y; }
    }
    s0 += __shfl_xor(s0, 4); s0 += __shfl_xor(s0, 8); s0 += __shfl_xor(s0, 16); s0 += __shfl_xor(s0, 32);
    s1 += __shfl_xor(s1, 4); s1 += __shfl_xor(s1, 8); s1 += __shfl_xor(s1, 16); s1 += __shfl_xor(s1, 32);
    s2 += __shfl_xor(s2, 4); s2 += __shfl_xor(s2, 8); s2 += __shfl_xor(s2, 16); s2 += __shfl_xor(s2, 32);
    s3 += __shfl_xor(s3, 4); s3 += __shfl_xor(s3, 8); s3 += __shfl_xor(s3, 16); s3 += __shfl_xor(s3, 32);
    if (q == 0) {
        float dv = dinv[node];
        int f = l << 2;
        float v0 = (f + 0 < 10) ? s0 * dv + bias[f + 0] : -1e30f;
        float v1 = (f + 1 < 10) ? s1 * dv + bias[f + 1] : -1e30f;
        float v2 = (f + 2 < 10) ? s2 * dv + bias[f + 2] : -1e30f;
        float v3 = (f + 3 < 10) ? s3 * dv + bias[f + 3] : -1e30f;
        float m = fmaxf(fmaxf(v0, v1), fmaxf(v2, v3));
        m = fmaxf(m, __shfl_xor(m, 1));
        m = fmaxf(m, __shfl_xor(m, 2));
        float ex = 0.f;
        if (f + 0 < 10) ex += __expf(v0 - m);
        if (f + 1 < 10) ex += __expf(v1 - m);
        if (f + 2 < 10) ex += __expf(v2 - m);
        if (f + 3 < 10) ex += __expf(v3 - m);
        ex += __shfl_xor(ex, 1);
        ex += __shfl_xor(ex, 2);
        float ls = __logf(ex);
        float* op = out + (size_t)node * 10;
        if (f + 0 < 10) op[f + 0] = v0 - m - ls;
        if (f + 1 < 10) op[f + 1] = v1 - m - ls;
        if (f + 2 < 10) op[f + 2] = v2 - m - ls;
        if (f + 3 < 10) op[f + 3] = v3 - m - ls;
    }
}

extern "C" void kernel_launch(void* const* d_in, const int* in_sizes, int n_in,
                              void* d_out, int out_size, void* d_ws, size_t ws_size,
                              hipStream_t stream) {
    const float* x  = (const float*)d_in[0];
    const int*   ei = (const int*)d_in[1];
    const float* W1 = (const float*)d_in[2];
    const float* b1 = (const float*)d_in[3];
    const float* W2 = (const float*)d_in[4];
    const float* b2 = (const float*)d_in[5];
    const float* W3 = (const float*)d_in[6];
    const float* b3 = (const float*)d_in[7];
    float* out = (float*)d_out;

    const int N = in_sizes[0] / 13;
    const int E = in_sizes[1] / 2;
    const int* src = ei;
    const int* dst = ei + E;

    char* p = (char*)d_ws;
    auto alloc = [&](size_t bytes) -> void* {
        void* r = (void*)p;
        p += (bytes + 255) & ~(size_t)255;
        return r;
    };
    int*   counts   = (int*)alloc((size_t)N * 4);
    int*   rowptr   = (int*)alloc((size_t)N * 4);
    int*   rowend   = (int*)alloc((size_t)N * 4);
    int*   partials = (int*)alloc(512);
    int*   csr_src  = (int*)alloc((size_t)E * 4);
    float* dinv     = (float*)alloc((size_t)N * 4);
    __half* G       = (__half*)alloc((size_t)N * 64 * 2);  // also hosts xs, a1, G3 (time-shared)
    float* x1       = (float*)alloc((size_t)N * 64 * 4);
    float* x2       = (float*)alloc((size_t)N * 64 * 4);

    __half* xs = G;                               // [N,16] half — dead once a1 built
    float*  a1 = (float*)((char*)G + (size_t)N * 32);  // [N,16] f32 — fits in G region
    __half* G3 = G;                               // [N,16] half — reuses G space
    unsigned* pack = (unsigned*)x2;               // [E] packed (rank,src) — dead before x2 written

    hipMemsetAsync(counts, 0, (size_t)N * 4, stream);

    int eb = (E + 255) / 256;
    int nch = (N + 1023) / 1024;

    hist_kernel<<<eb, 256, 0, stream>>>(src, dst, counts, pack, E);
    scan1_kernel<<<nch, 256, 0, stream>>>(counts, rowptr, partials, N);
    scan2_kernel<<<1, 128, 0, stream>>>(partials, nch);

    int rb4 = (N + 3) / 4;
    int rb16 = (N + 15) / 16;
    int rb32 = (N + 31) / 32;
    int sb = (N * 16 + 255) / 256;

    // scan3 merged: rowptr/rowend finalize + dinv + conv1 pre-scale (A·(XW) == (A·X)·W)
    scan3_kernel<<<sb, 256, 0, stream>>>(rowptr, partials, counts, rowend, dinv, x, xs, N);
    fillx_kernel<<<2048, 256, 0, stream>>>(dst, pack, rowptr, csr_src, E, N);

    // conv1: aggregate 13-wide first, then matmul
    agg16_kernel<<<rb4, 256, 0, stream>>>(xs, rowptr, rowend, csr_src, dinv, a1, N);
    matmul13_kernel<<<rb4, 256, 0, stream>>>(a1, W1, b1, x1, N);

    // conv2: 64 -> 64, ReLU + residual (x2 = relu(conv2) + x1)
    matmul_scale64<<<rb32, 256, 0, stream>>>(x1, W2, dinv, G, N);
    agg64_kernel<true, true><<<rb4, 256, 0, stream>>>(G, rowptr, rowend, csr_src, dinv, b2, x1, x2, N);

    // conv3: 64 -> 10 (padded 16) + log_softmax
    matmul_scale10<<<rb16, 256, 0, stream>>>(x2, W3, dinv, G3, N);
    agg10_lsm_kernel<<<rb4, 256, 0, stream>>>(G3, rowptr, rowend, csr_src, dinv, b3, out, N);
}

// Round 10
// 289.151 us; speedup vs baseline: 1.0857x; 1.0857x over previous
//
#include <hip/hip_runtime.h>
#include <hip/hip_fp16.h>
#include <math.h>

// ---------------- degree histogram + per-edge rank + packed (rank,src) ----------------
__global__ void hist_kernel(const int* __restrict__ src, const int* __restrict__ dst,
                            int* __restrict__ counts, unsigned* __restrict__ pack, int E) {
    int e = blockIdx.x * blockDim.x + threadIdx.x;
    if (e < E) {
        int r = atomicAdd(&counts[dst[e]], 1);
        pack[e] = ((unsigned)r << 17) | (unsigned)src[e];
    }
}

// ---------------- exclusive scan ----------------
__global__ void scan1_kernel(const int* __restrict__ counts, int* __restrict__ rowptr,
                             int* __restrict__ partials, int n) {
    __shared__ int tsum[256];
    int chunk = blockIdx.x;
    int base = chunk * 1024;
    int t = threadIdx.x;
    int v[4];
    int s = 0;
    #pragma unroll
    for (int j = 0; j < 4; ++j) {
        int idx = base + t * 4 + j;
        v[j] = (idx < n) ? counts[idx] : 0;
        s += v[j];
    }
    tsum[t] = s;
    __syncthreads();
    for (int off = 1; off < 256; off <<= 1) {
        int add = (t >= off) ? tsum[t - off] : 0;
        __syncthreads();
        tsum[t] += add;
        __syncthreads();
    }
    if (t == 255) partials[chunk] = tsum[255];
    int run = (t == 0) ? 0 : tsum[t - 1];
    #pragma unroll
    for (int j = 0; j < 4; ++j) {
        int idx = base + t * 4 + j;
        if (idx < n) rowptr[idx] = run;
        run += v[j];
    }
}

__global__ void scan2_kernel(int* __restrict__ partials, int nch) {
    __shared__ int s[128];
    int t = threadIdx.x;  // blockDim = 128
    s[t] = (t < nch) ? partials[t] : 0;
    __syncthreads();
    for (int off = 1; off < 128; off <<= 1) {
        int add = (t >= off) ? s[t - off] : 0;
        __syncthreads();
        s[t] += add;
        __syncthreads();
    }
    if (t < nch) partials[t] = (t == 0) ? 0 : s[t - 1];
}

// scan3 (merged): finalize rowptr/rowend, dinv, and conv1 pre-scale xs[n,16].
__global__ void scan3_kernel(int* __restrict__ rowptr, const int* __restrict__ partials,
                             const int* __restrict__ counts, int* __restrict__ rowend,
                             float* __restrict__ dinv, const float* __restrict__ x,
                             __half* __restrict__ xs, int n) {
    int i = blockIdx.x * blockDim.x + threadIdx.x;
    if (i >= n * 16) return;
    int node = i >> 4, c = i & 15;
    int cnt = counts[node];
    float dv = rsqrtf((float)cnt + 1.0f);
    if (c == 0) {
        int v = rowptr[node] + partials[node >> 10];
        rowptr[node] = v;
        rowend[node] = v + cnt;
        dinv[node] = dv;
    }
    float xv = (c < 13) ? x[node * 13 + c] * dv : 0.f;
    xs[i] = __float2half(xv);
}

// ---------------- CSR fill: atomic-free, XCD-partitioned ----------------
__global__ void fillx_kernel(const int* __restrict__ dst, const unsigned* __restrict__ pack,
                             const int* __restrict__ rowptr, int* __restrict__ csr_src,
                             int E, int N) {
    int x = blockIdx.x & 7;
    int grp = blockIdx.x >> 3;
    int ngrp = gridDim.x >> 3;
    int lo = (int)(((long long)N * x) >> 3);
    int hi = (int)(((long long)N * (x + 1)) >> 3);
    int chunk = (E + ngrp - 1) / ngrp;
    int e0 = grp * chunk;
    int e1 = min(E, e0 + chunk);
    for (int e = e0 + (int)threadIdx.x; e < e1; e += (int)blockDim.x) {
        int d = dst[e];
        if (d >= lo && d < hi) {
            unsigned w = pack[e];
            csr_src[rowptr[d] + (int)(w >> 17)] = (int)(w & 0x1FFFFu);
        }
    }
}

// ---------------- 16-wide aggregation (R7-proven): 16 nodes/block, 16 lanes/node ----------------
__global__ void agg16_kernel(const __half* __restrict__ xs, const int* __restrict__ rowptr,
                             const int* __restrict__ rowend, const int* __restrict__ csr_src,
                             const float* __restrict__ dinv, float* __restrict__ a1, int n) {
    int node = blockIdx.x * 16 + (threadIdx.x >> 4);
    int lane = threadIdx.x & 15;
    if (node >= n) return;
    float s = __half2float(xs[(size_t)node * 16 + lane]);
    int e0 = rowptr[node], end = rowend[node];
    for (int base = e0; base < end; base += 8) {
        #pragma unroll
        for (int j = 0; j < 8; ++j) {
            int idx = base + j;
            int sj = csr_src[idx < end ? idx : end - 1];
            float g = __half2float(xs[(size_t)sj * 16 + lane]);
            if (idx < end) s += g;
        }
    }
    a1[(size_t)node * 16 + lane] = s * dinv[node];
}

// ---------------- conv1 matmul: x1 = relu(a1 @ W1 + b1), K=13 (stride 16) ----------------
__global__ void matmul13_kernel(const float* __restrict__ a1, const float* __restrict__ W1,
                                const float* __restrict__ b1, float* __restrict__ x1, int n) {
    __shared__ float w[13 * 64];
    for (int i = threadIdx.x; i < 13 * 64; i += 256) w[i] = W1[i];
    __syncthreads();
    int row = blockIdx.x * 4 + (threadIdx.x >> 6);
    int col = threadIdx.x & 63;
    if (row >= n) return;
    const float* ar = a1 + (size_t)row * 16;
    float acc = b1[col];
    #pragma unroll
    for (int k = 0; k < 13; ++k) acc = fmaf(ar[k], w[k * 64 + col], acc);
    x1[(size_t)row * 64 + col] = fmaxf(acc, 0.f);
}

// ---------------- conv2 matmul: register-resident W, K split across quarters ----------------
__global__ void matmul_scale64(const float* __restrict__ X, const float* __restrict__ W,
                               const float* __restrict__ dinv, __half* __restrict__ G, int n) {
    int lane = threadIdx.x & 63;
    int wave = threadIdx.x >> 6;  // 0..3
    int f = lane & 15, q = lane >> 4;
    const float4* W4 = (const float4*)W;  // W[64][64] -> W4[k*16 + c4]
    float4 wr[16];
    #pragma unroll
    for (int kk = 0; kk < 16; ++kk) wr[kk] = W4[(q * 16 + kk) * 16 + f];
    int base = blockIdx.x * 32 + wave * 8;
    #pragma unroll 2
    for (int r = 0; r < 8; ++r) {
        int row = base + r;
        if (row >= n) break;
        const float4* xr = (const float4*)(X + (size_t)row * 64);
        float4 xa = xr[q * 4 + 0], xb = xr[q * 4 + 1];
        float4 xc = xr[q * 4 + 2], xd = xr[q * 4 + 3];
        float xv[16] = {xa.x, xa.y, xa.z, xa.w, xb.x, xb.y, xb.z, xb.w,
                        xc.x, xc.y, xc.z, xc.w, xd.x, xd.y, xd.z, xd.w};
        float a0 = 0.f, a1_ = 0.f, a2 = 0.f, a3 = 0.f;
        #pragma unroll
        for (int kk = 0; kk < 16; ++kk) {
            a0 = fmaf(xv[kk], wr[kk].x, a0);
            a1_ = fmaf(xv[kk], wr[kk].y, a1_);
            a2 = fmaf(xv[kk], wr[kk].z, a2);
            a3 = fmaf(xv[kk], wr[kk].w, a3);
        }
        a0 += __shfl_xor(a0, 16); a0 += __shfl_xor(a0, 32);
        a1_ += __shfl_xor(a1_, 16); a1_ += __shfl_xor(a1_, 32);
        a2 += __shfl_xor(a2, 16); a2 += __shfl_xor(a2, 32);
        a3 += __shfl_xor(a3, 16); a3 += __shfl_xor(a3, 32);
        if (q == 0) {
            float dv = dinv[row];
            union { __half2 h[2]; float2 fx; } u;
            u.h[0] = __floats2half2_rn(a0 * dv, a1_ * dv);
            u.h[1] = __floats2half2_rn(a2 * dv, a3 * dv);
            *(float2*)((char*)G + ((size_t)row << 7) + (f << 3)) = u.fx;
        }
    }
}

// conv3 matmul: 64 -> 10, padded to 16 cols (pad cols written as 0), half output
__global__ void matmul_scale10(const float* __restrict__ X, const float* __restrict__ W,
                               const float* __restrict__ dinv, __half* __restrict__ G, int n) {
    __shared__ float w[64 * 10];
    for (int i = threadIdx.x; i < 640; i += 256) w[i] = W[i];
    __syncthreads();
    int row = blockIdx.x * 16 + (threadIdx.x >> 4);
    int col = threadIdx.x & 15;
    if (row >= n) return;
    float r = 0.f;
    if (col < 10) {
        const float* xr = X + (size_t)row * 64;
        float acc = 0.f;
        #pragma unroll
        for (int k = 0; k < 64; ++k) acc = fmaf(xr[k], w[k * 10 + col], acc);
        r = acc * dinv[row];
    }
    G[(size_t)row * 16 + col] = __float2half(r);
}

// ---------------- 64-wide aggregation (R7-proven): 4 edges/instr, quarters, clamped ----------------
template <bool RELU, bool RESID>
__global__ void agg64_kernel(const __half* __restrict__ G, const int* __restrict__ rowptr,
                             const int* __restrict__ rowend, const int* __restrict__ csr_src,
                             const float* __restrict__ dinv, const float* __restrict__ bias,
                             const float* __restrict__ resid, float* __restrict__ out, int n) {
    int node = __builtin_amdgcn_readfirstlane(blockIdx.x * 4 + (int)(threadIdx.x >> 6));
    int lane = threadIdx.x & 63;
    if (node >= n) return;
    int q  = lane >> 4;   // edge slot within 4-edge packet
    int f4 = lane & 15;   // feature group: features [f4*4, f4*4+4)
    const char* Gb = (const char*)G;
    float s0 = 0.f, s1 = 0.f, s2 = 0.f, s3 = 0.f;
    if (q == 0) {  // self-loop term, quarter 0 only
        float2 raw = *(const float2*)(Gb + ((size_t)node << 7) + (f4 << 3));
        union { float2 f; __half2 h[2]; } u; u.f = raw;
        float2 a = __half22float2(u.h[0]), b = __half22float2(u.h[1]);
        s0 = a.x; s1 = a.y; s2 = b.x; s3 = b.y;
    }
    int e0 = rowptr[node], end = rowend[node];
    for (int base = e0; base < end; base += 16) {
        #pragma unroll
        for (int uu = 0; uu < 4; ++uu) {
            int idx = base + uu * 4 + q;
            int sj = csr_src[idx < end ? idx : end - 1];  // uniform within quarter
            float2 raw = *(const float2*)(Gb + ((size_t)sj << 7) + (f4 << 3));
            union { float2 f; __half2 h[2]; } u; u.f = raw;
            float2 a = __half22float2(u.h[0]), b = __half22float2(u.h[1]);
            if (idx < end) { s0 += a.x; s1 += a.y; s2 += b.x; s3 += b.y; }
        }
    }
    s0 += __shfl_xor(s0, 16); s0 += __shfl_xor(s0, 32);
    s1 += __shfl_xor(s1, 16); s1 += __shfl_xor(s1, 32);
    s2 += __shfl_xor(s2, 16); s2 += __shfl_xor(s2, 32);
    s3 += __shfl_xor(s3, 16); s3 += __shfl_xor(s3, 32);
    if (q == 0) {
        float dv = dinv[node];
        float4 bb = *(const float4*)(bias + (f4 << 2));
        float v0 = s0 * dv + bb.x, v1 = s1 * dv + bb.y;
        float v2 = s2 * dv + bb.z, v3 = s3 * dv + bb.w;
        if (RELU) {
            v0 = fmaxf(v0, 0.f); v1 = fmaxf(v1, 0.f);
            v2 = fmaxf(v2, 0.f); v3 = fmaxf(v3, 0.f);
        }
        if (RESID) {
            float4 rr = *(const float4*)(resid + ((size_t)node << 6) + (f4 << 2));
            v0 += rr.x; v1 += rr.y; v2 += rr.z; v3 += rr.w;
        }
        float4 o; o.x = v0; o.y = v1; o.z = v2; o.w = v3;
        *(float4*)(out + ((size_t)node << 6) + (f4 << 2)) = o;
    }
}

// ---------------- final aggregation (R7-proven, 16 lanes/node) + fused log_softmax ----------------
__global__ void agg10_lsm_kernel(const __half* __restrict__ G, const int* __restrict__ rowptr,
                                 const int* __restrict__ rowend, const int* __restrict__ csr_src,
                                 const float* __restrict__ dinv, const float* __restrict__ bias,
                                 float* __restrict__ out, int n) {
    int node = blockIdx.x * 16 + (threadIdx.x >> 4);
    int lane = threadIdx.x & 15;
    if (node >= n) return;
    bool act = lane < 10;
    float s = __half2float(G[(size_t)node * 16 + lane]);  // pad cols hold 0
    int e0 = rowptr[node], end = rowend[node];
    for (int base = e0; base < end; base += 8) {
        #pragma unroll
        for (int j = 0; j < 8; ++j) {
            int idx = base + j;
            int sj = csr_src[idx < end ? idx : end - 1];
            float g = __half2float(G[(size_t)sj * 16 + lane]);
            if (idx < end) s += g;
        }
    }
    float v = act ? (s * dinv[node] + bias[lane < 10 ? lane : 9]) : -1e30f;
    float m = v;
    #pragma unroll
    for (int off = 8; off; off >>= 1) m = fmaxf(m, __shfl_xor(m, off, 16));
    float ex = act ? __expf(v - m) : 0.f;
    float sum = ex;
    #pragma unroll
    for (int off = 8; off; off >>= 1) sum += __shfl_xor(sum, off, 16);
    if (act) out[(size_t)node * 10 + lane] = v - m - __logf(sum);
}

extern "C" void kernel_launch(void* const* d_in, const int* in_sizes, int n_in,
                              void* d_out, int out_size, void* d_ws, size_t ws_size,
                              hipStream_t stream) {
    const float* x  = (const float*)d_in[0];
    const int*   ei = (const int*)d_in[1];
    const float* W1 = (const float*)d_in[2];
    const float* b1 = (const float*)d_in[3];
    const float* W2 = (const float*)d_in[4];
    const float* b2 = (const float*)d_in[5];
    const float* W3 = (const float*)d_in[6];
    const float* b3 = (const float*)d_in[7];
    float* out = (float*)d_out;

    const int N = in_sizes[0] / 13;
    const int E = in_sizes[1] / 2;
    const int* src = ei;
    const int* dst = ei + E;

    char* p = (char*)d_ws;
    auto alloc = [&](size_t bytes) -> void* {
        void* r = (void*)p;
        p += (bytes + 255) & ~(size_t)255;
        return r;
    };
    int*   counts   = (int*)alloc((size_t)N * 4);
    int*   rowptr   = (int*)alloc((size_t)N * 4);
    int*   rowend   = (int*)alloc((size_t)N * 4);
    int*   partials = (int*)alloc(512);
    int*   csr_src  = (int*)alloc((size_t)E * 4);
    float* dinv     = (float*)alloc((size_t)N * 4);
    __half* G       = (__half*)alloc((size_t)N * 64 * 2);  // also hosts xs, a1, G3 (time-shared)
    float* x1       = (float*)alloc((size_t)N * 64 * 4);
    float* x2       = (float*)alloc((size_t)N * 64 * 4);

    __half* xs = G;                               // [N,16] half — dead once a1 built
    float*  a1 = (float*)((char*)G + (size_t)N * 32);  // [N,16] f32 — fits in G region
    __half* G3 = G;                               // [N,16] half — reuses G space
    unsigned* pack = (unsigned*)x2;               // [E] packed (rank,src) — dead before x2 written

    hipMemsetAsync(counts, 0, (size_t)N * 4, stream);

    int eb = (E + 255) / 256;
    int nch = (N + 1023) / 1024;

    hist_kernel<<<eb, 256, 0, stream>>>(src, dst, counts, pack, E);
    scan1_kernel<<<nch, 256, 0, stream>>>(counts, rowptr, partials, N);
    scan2_kernel<<<1, 128, 0, stream>>>(partials, nch);

    int rb4 = (N + 3) / 4;
    int rb16 = (N + 15) / 16;
    int rb32 = (N + 31) / 32;
    int sb = (N * 16 + 255) / 256;

    // scan3 merged: rowptr/rowend finalize + dinv + conv1 pre-scale (A·(XW) == (A·X)·W)
    scan3_kernel<<<sb, 256, 0, stream>>>(rowptr, partials, counts, rowend, dinv, x, xs, N);
    fillx_kernel<<<2048, 256, 0, stream>>>(dst, pack, rowptr, csr_src, E, N);

    // conv1: aggregate 13-wide first, then matmul
    agg16_kernel<<<rb16, 256, 0, stream>>>(xs, rowptr, rowend, csr_src, dinv, a1, N);
    matmul13_kernel<<<rb4, 256, 0, stream>>>(a1, W1, b1, x1, N);

    // conv2: 64 -> 64, ReLU + residual (x2 = relu(conv2) + x1)
    matmul_scale64<<<rb32, 256, 0, stream>>>(x1, W2, dinv, G, N);
    agg64_kernel<true, true><<<rb4, 256, 0, stream>>>(G, rowptr, rowend, csr_src, dinv, b2, x1, x2, N);

    // conv3: 64 -> 10 (padded 16) + log_softmax
    matmul_scale10<<<rb16, 256, 0, stream>>>(x2, W3, dinv, G3, N);
    agg10_lsm_kernel<<<rb16, 256, 0, stream>>>(G3, rowptr, rowend, csr_src, dinv, b3, out, N);
}

// Round 11
// 288.248 us; speedup vs baseline: 1.0891x; 1.0031x over previous
//
#include <hip/hip_runtime.h>
#include <hip/hip_fp16.h>
#include <math.h>

// ---------------- degree histogram + per-edge rank + packed (rank,src) ----------------
__global__ void hist_kernel(const int* __restrict__ src, const int* __restrict__ dst,
                            int* __restrict__ counts, unsigned* __restrict__ pack, int E) {
    int e = blockIdx.x * blockDim.x + threadIdx.x;
    if (e < E) {
        int r = atomicAdd(&counts[dst[e]], 1);
        pack[e] = ((unsigned)r << 17) | (unsigned)src[e];
    }
}

// ---------------- exclusive scan ----------------
__global__ void scan1_kernel(const int* __restrict__ counts, int* __restrict__ rowptr,
                             int* __restrict__ partials, int n) {
    __shared__ int tsum[256];
    int chunk = blockIdx.x;
    int base = chunk * 1024;
    int t = threadIdx.x;
    int v[4];
    int s = 0;
    #pragma unroll
    for (int j = 0; j < 4; ++j) {
        int idx = base + t * 4 + j;
        v[j] = (idx < n) ? counts[idx] : 0;
        s += v[j];
    }
    tsum[t] = s;
    __syncthreads();
    for (int off = 1; off < 256; off <<= 1) {
        int add = (t >= off) ? tsum[t - off] : 0;
        __syncthreads();
        tsum[t] += add;
        __syncthreads();
    }
    if (t == 255) partials[chunk] = tsum[255];
    int run = (t == 0) ? 0 : tsum[t - 1];
    #pragma unroll
    for (int j = 0; j < 4; ++j) {
        int idx = base + t * 4 + j;
        if (idx < n) rowptr[idx] = run;
        run += v[j];
    }
}

__global__ void scan2_kernel(int* __restrict__ partials, int nch) {
    __shared__ int s[128];
    int t = threadIdx.x;  // blockDim = 128
    s[t] = (t < nch) ? partials[t] : 0;
    __syncthreads();
    for (int off = 1; off < 128; off <<= 1) {
        int add = (t >= off) ? s[t - off] : 0;
        __syncthreads();
        s[t] += add;
        __syncthreads();
    }
    if (t < nch) partials[t] = (t == 0) ? 0 : s[t - 1];
}

// scan3 (merged): finalize rowptr/rowend, dinv, and conv1 pre-scale xs[n,16].
__global__ void scan3_kernel(int* __restrict__ rowptr, const int* __restrict__ partials,
                             const int* __restrict__ counts, int* __restrict__ rowend,
                             float* __restrict__ dinv, const float* __restrict__ x,
                             __half* __restrict__ xs, int n) {
    int i = blockIdx.x * blockDim.x + threadIdx.x;
    if (i >= n * 16) return;
    int node = i >> 4, c = i & 15;
    int cnt = counts[node];
    float dv = rsqrtf((float)cnt + 1.0f);
    if (c == 0) {
        int v = rowptr[node] + partials[node >> 10];
        rowptr[node] = v;
        rowend[node] = v + cnt;
        dinv[node] = dv;
    }
    float xv = (c < 13) ? x[node * 13 + c] * dv : 0.f;
    xs[i] = __float2half(xv);
}

// ---------------- CSR fill: atomic-free, 4-way partitioned (2 XCDs per partition) ----------------
__global__ void fillx_kernel(const int* __restrict__ dst, const unsigned* __restrict__ pack,
                             const int* __restrict__ rowptr, int* __restrict__ csr_src,
                             int E, int N) {
    int x = blockIdx.x & 3;
    int grp = blockIdx.x >> 2;
    int ngrp = gridDim.x >> 2;
    int lo = (int)(((long long)N * x) >> 2);
    int hi = (int)(((long long)N * (x + 1)) >> 2);
    int chunk = (E + ngrp - 1) / ngrp;
    int e0 = grp * chunk;
    int e1 = min(E, e0 + chunk);
    for (int e = e0 + (int)threadIdx.x; e < e1; e += (int)blockDim.x) {
        int d = dst[e];
        if (d >= lo && d < hi) {
            unsigned w = pack[e];
            csr_src[rowptr[d] + (int)(w >> 17)] = (int)(w & 0x1FFFFu);
        }
    }
}

// ---------------- 16-wide aggregation (R7-proven): 16 nodes/block, 16 lanes/node ----------------
__global__ void agg16_kernel(const __half* __restrict__ xs, const int* __restrict__ rowptr,
                             const int* __restrict__ rowend, const int* __restrict__ csr_src,
                             const float* __restrict__ dinv, float* __restrict__ a1, int n) {
    int node = blockIdx.x * 16 + (threadIdx.x >> 4);
    int lane = threadIdx.x & 15;
    if (node >= n) return;
    float s = __half2float(xs[(size_t)node * 16 + lane]);
    int e0 = rowptr[node], end = rowend[node];
    for (int base = e0; base < end; base += 8) {
        #pragma unroll
        for (int j = 0; j < 8; ++j) {
            int idx = base + j;
            int sj = csr_src[idx < end ? idx : end - 1];
            float g = __half2float(xs[(size_t)sj * 16 + lane]);
            if (idx < end) s += g;
        }
    }
    a1[(size_t)node * 16 + lane] = s * dinv[node];
}

// ---------------- conv1 matmul: x1 = relu(a1 @ W1 + b1), K=13 (stride 16) ----------------
__global__ void matmul13_kernel(const float* __restrict__ a1, const float* __restrict__ W1,
                                const float* __restrict__ b1, float* __restrict__ x1, int n) {
    __shared__ float w[13 * 64];
    for (int i = threadIdx.x; i < 13 * 64; i += 256) w[i] = W1[i];
    __syncthreads();
    int row = blockIdx.x * 4 + (threadIdx.x >> 6);
    int col = threadIdx.x & 63;
    if (row >= n) return;
    const float* ar = a1 + (size_t)row * 16;
    float acc = b1[col];
    #pragma unroll
    for (int k = 0; k < 13; ++k) acc = fmaf(ar[k], w[k * 64 + col], acc);
    x1[(size_t)row * 64 + col] = fmaxf(acc, 0.f);
}

// ---------------- conv2 matmul: register-resident W, K split across quarters ----------------
__global__ void matmul_scale64(const float* __restrict__ X, const float* __restrict__ W,
                               const float* __restrict__ dinv, __half* __restrict__ G, int n) {
    int lane = threadIdx.x & 63;
    int wave = threadIdx.x >> 6;  // 0..3
    int f = lane & 15, q = lane >> 4;
    const float4* W4 = (const float4*)W;  // W[64][64] -> W4[k*16 + c4]
    float4 wr[16];
    #pragma unroll
    for (int kk = 0; kk < 16; ++kk) wr[kk] = W4[(q * 16 + kk) * 16 + f];
    int base = blockIdx.x * 32 + wave * 8;
    #pragma unroll 2
    for (int r = 0; r < 8; ++r) {
        int row = base + r;
        if (row >= n) break;
        const float4* xr = (const float4*)(X + (size_t)row * 64);
        float4 xa = xr[q * 4 + 0], xb = xr[q * 4 + 1];
        float4 xc = xr[q * 4 + 2], xd = xr[q * 4 + 3];
        float xv[16] = {xa.x, xa.y, xa.z, xa.w, xb.x, xb.y, xb.z, xb.w,
                        xc.x, xc.y, xc.z, xc.w, xd.x, xd.y, xd.z, xd.w};
        float a0 = 0.f, a1_ = 0.f, a2 = 0.f, a3 = 0.f;
        #pragma unroll
        for (int kk = 0; kk < 16; ++kk) {
            a0 = fmaf(xv[kk], wr[kk].x, a0);
            a1_ = fmaf(xv[kk], wr[kk].y, a1_);
            a2 = fmaf(xv[kk], wr[kk].z, a2);
            a3 = fmaf(xv[kk], wr[kk].w, a3);
        }
        a0 += __shfl_xor(a0, 16); a0 += __shfl_xor(a0, 32);
        a1_ += __shfl_xor(a1_, 16); a1_ += __shfl_xor(a1_, 32);
        a2 += __shfl_xor(a2, 16); a2 += __shfl_xor(a2, 32);
        a3 += __shfl_xor(a3, 16); a3 += __shfl_xor(a3, 32);
        if (q == 0) {
            float dv = dinv[row];
            union { __half2 h[2]; float2 fx; } u;
            u.h[0] = __floats2half2_rn(a0 * dv, a1_ * dv);
            u.h[1] = __floats2half2_rn(a2 * dv, a3 * dv);
            *(float2*)((char*)G + ((size_t)row << 7) + (f << 3)) = u.fx;
        }
    }
}

// conv3 matmul: 64 -> 10, padded to 16 cols (pad cols written as 0), half output
__global__ void matmul_scale10(const float* __restrict__ X, const float* __restrict__ W,
                               const float* __restrict__ dinv, __half* __restrict__ G, int n) {
    __shared__ float w[64 * 10];
    for (int i = threadIdx.x; i < 640; i += 256) w[i] = W[i];
    __syncthreads();
    int row = blockIdx.x * 16 + (threadIdx.x >> 4);
    int col = threadIdx.x & 15;
    if (row >= n) return;
    float r = 0.f;
    if (col < 10) {
        const float* xr = X + (size_t)row * 64;
        float acc = 0.f;
        #pragma unroll
        for (int k = 0; k < 64; ++k) acc = fmaf(xr[k], w[k * 10 + col], acc);
        r = acc * dinv[row];
    }
    G[(size_t)row * 16 + col] = __float2half(r);
}

// ---------------- 64-wide aggregation: 4 edges/instr, quarters, clamped, unroll-8 ----------------
template <bool RELU, bool RESID>
__global__ void agg64_kernel(const __half* __restrict__ G, const int* __restrict__ rowptr,
                             const int* __restrict__ rowend, const int* __restrict__ csr_src,
                             const float* __restrict__ dinv, const float* __restrict__ bias,
                             const float* __restrict__ resid, float* __restrict__ out, int n) {
    int node = __builtin_amdgcn_readfirstlane(blockIdx.x * 4 + (int)(threadIdx.x >> 6));
    int lane = threadIdx.x & 63;
    if (node >= n) return;
    int q  = lane >> 4;   // edge slot within 4-edge packet
    int f4 = lane & 15;   // feature group: features [f4*4, f4*4+4)
    const char* Gb = (const char*)G;
    float s0 = 0.f, s1 = 0.f, s2 = 0.f, s3 = 0.f;
    if (q == 0) {  // self-loop term, quarter 0 only
        float2 raw = *(const float2*)(Gb + ((size_t)node << 7) + (f4 << 3));
        union { float2 f; __half2 h[2]; } u; u.f = raw;
        float2 a = __half22float2(u.h[0]), b = __half22float2(u.h[1]);
        s0 = a.x; s1 = a.y; s2 = b.x; s3 = b.y;
    }
    int e0 = rowptr[node], end = rowend[node];
    for (int base = e0; base < end; base += 32) {
        #pragma unroll
        for (int uu = 0; uu < 8; ++uu) {
            int idx = base + uu * 4 + q;
            int sj = csr_src[idx < end ? idx : end - 1];  // uniform within quarter
            float2 raw = *(const float2*)(Gb + ((size_t)sj << 7) + (f4 << 3));
            union { float2 f; __half2 h[2]; } u; u.f = raw;
            float2 a = __half22float2(u.h[0]), b = __half22float2(u.h[1]);
            if (idx < end) { s0 += a.x; s1 += a.y; s2 += b.x; s3 += b.y; }
        }
    }
    s0 += __shfl_xor(s0, 16); s0 += __shfl_xor(s0, 32);
    s1 += __shfl_xor(s1, 16); s1 += __shfl_xor(s1, 32);
    s2 += __shfl_xor(s2, 16); s2 += __shfl_xor(s2, 32);
    s3 += __shfl_xor(s3, 16); s3 += __shfl_xor(s3, 32);
    if (q == 0) {
        float dv = dinv[node];
        float4 bb = *(const float4*)(bias + (f4 << 2));
        float v0 = s0 * dv + bb.x, v1 = s1 * dv + bb.y;
        float v2 = s2 * dv + bb.z, v3 = s3 * dv + bb.w;
        if (RELU) {
            v0 = fmaxf(v0, 0.f); v1 = fmaxf(v1, 0.f);
            v2 = fmaxf(v2, 0.f); v3 = fmaxf(v3, 0.f);
        }
        if (RESID) {
            float4 rr = *(const float4*)(resid + ((size_t)node << 6) + (f4 << 2));
            v0 += rr.x; v1 += rr.y; v2 += rr.z; v3 += rr.w;
        }
        float4 o; o.x = v0; o.y = v1; o.z = v2; o.w = v3;
        *(float4*)(out + ((size_t)node << 6) + (f4 << 2)) = o;
    }
}

// ---------------- final aggregation (R7-proven, 16 lanes/node) + fused log_softmax ----------------
__global__ void agg10_lsm_kernel(const __half* __restrict__ G, const int* __restrict__ rowptr,
                                 const int* __restrict__ rowend, const int* __restrict__ csr_src,
                                 const float* __restrict__ dinv, const float* __restrict__ bias,
                                 float* __restrict__ out, int n) {
    int node = blockIdx.x * 16 + (threadIdx.x >> 4);
    int lane = threadIdx.x & 15;
    if (node >= n) return;
    bool act = lane < 10;
    float s = __half2float(G[(size_t)node * 16 + lane]);  // pad cols hold 0
    int e0 = rowptr[node], end = rowend[node];
    for (int base = e0; base < end; base += 8) {
        #pragma unroll
        for (int j = 0; j < 8; ++j) {
            int idx = base + j;
            int sj = csr_src[idx < end ? idx : end - 1];
            float g = __half2float(G[(size_t)sj * 16 + lane]);
            if (idx < end) s += g;
        }
    }
    float v = act ? (s * dinv[node] + bias[lane < 10 ? lane : 9]) : -1e30f;
    float m = v;
    #pragma unroll
    for (int off = 8; off; off >>= 1) m = fmaxf(m, __shfl_xor(m, off, 16));
    float ex = act ? __expf(v - m) : 0.f;
    float sum = ex;
    #pragma unroll
    for (int off = 8; off; off >>= 1) sum += __shfl_xor(sum, off, 16);
    if (act) out[(size_t)node * 10 + lane] = v - m - __logf(sum);
}

extern "C" void kernel_launch(void* const* d_in, const int* in_sizes, int n_in,
                              void* d_out, int out_size, void* d_ws, size_t ws_size,
                              hipStream_t stream) {
    const float* x  = (const float*)d_in[0];
    const int*   ei = (const int*)d_in[1];
    const float* W1 = (const float*)d_in[2];
    const float* b1 = (const float*)d_in[3];
    const float* W2 = (const float*)d_in[4];
    const float* b2 = (const float*)d_in[5];
    const float* W3 = (const float*)d_in[6];
    const float* b3 = (const float*)d_in[7];
    float* out = (float*)d_out;

    const int N = in_sizes[0] / 13;
    const int E = in_sizes[1] / 2;
    const int* src = ei;
    const int* dst = ei + E;

    char* p = (char*)d_ws;
    auto alloc = [&](size_t bytes) -> void* {
        void* r = (void*)p;
        p += (bytes + 255) & ~(size_t)255;
        return r;
    };
    int*   counts   = (int*)alloc((size_t)N * 4);
    int*   rowptr   = (int*)alloc((size_t)N * 4);
    int*   rowend   = (int*)alloc((size_t)N * 4);
    int*   partials = (int*)alloc(512);
    int*   csr_src  = (int*)alloc((size_t)E * 4);
    float* dinv     = (float*)alloc((size_t)N * 4);
    __half* G       = (__half*)alloc((size_t)N * 64 * 2);  // also hosts xs, a1, G3 (time-shared)
    float* x1       = (float*)alloc((size_t)N * 64 * 4);
    float* x2       = (float*)alloc((size_t)N * 64 * 4);

    __half* xs = G;                               // [N,16] half — dead once a1 built
    float*  a1 = (float*)((char*)G + (size_t)N * 32);  // [N,16] f32 — fits in G region
    __half* G3 = G;                               // [N,16] half — reuses G space
    unsigned* pack = (unsigned*)x2;               // [E] packed (rank,src) — dead before x2 written

    hipMemsetAsync(counts, 0, (size_t)N * 4, stream);

    int eb = (E + 255) / 256;
    int nch = (N + 1023) / 1024;

    hist_kernel<<<eb, 256, 0, stream>>>(src, dst, counts, pack, E);
    scan1_kernel<<<nch, 256, 0, stream>>>(counts, rowptr, partials, N);
    scan2_kernel<<<1, 128, 0, stream>>>(partials, nch);

    int rb4 = (N + 3) / 4;
    int rb16 = (N + 15) / 16;
    int rb32 = (N + 31) / 32;
    int sb = (N * 16 + 255) / 256;

    // scan3 merged: rowptr/rowend finalize + dinv + conv1 pre-scale (A·(XW) == (A·X)·W)
    scan3_kernel<<<sb, 256, 0, stream>>>(rowptr, partials, counts, rowend, dinv, x, xs, N);
    fillx_kernel<<<2048, 256, 0, stream>>>(dst, pack, rowptr, csr_src, E, N);

    // conv1: aggregate 13-wide first, then matmul
    agg16_kernel<<<rb16, 256, 0, stream>>>(xs, rowptr, rowend, csr_src, dinv, a1, N);
    matmul13_kernel<<<rb4, 256, 0, stream>>>(a1, W1, b1, x1, N);

    // conv2: 64 -> 64, ReLU + residual (x2 = relu(conv2) + x1)
    matmul_scale64<<<rb32, 256, 0, stream>>>(x1, W2, dinv, G, N);
    agg64_kernel<true, true><<<rb4, 256, 0, stream>>>(G, rowptr, rowend, csr_src, dinv, b2, x1, x2, N);

    // conv3: 64 -> 10 (padded 16) + log_softmax
    matmul_scale10<<<rb16, 256, 0, stream>>>(x2, W3, dinv, G3, N);
    agg10_lsm_kernel<<<rb16, 256, 0, stream>>>(G3, rowptr, rowend, csr_src, dinv, b3, out, N);
}